// Round 4
// baseline (455.276 us; speedup 1.0000x reference)
//
#include <hip/hip_runtime.h>
#include <hip/hip_bf16.h>
#include <stdint.h>

#define N 4096

typedef __attribute__((ext_vector_type(4))) float f32x4;
typedef __attribute__((ext_vector_type(8))) short s16x8;   // 8 bf16 lanes (4 VGPRs)

__device__ inline unsigned short f2bf(float f) {
    unsigned int u = __float_as_uint(f);
    u += 0x7fffu + ((u >> 16) & 1u);        // RNE
    return (unsigned short)(u >> 16);
}
__device__ inline float bf2f(unsigned short h) {
    return __uint_as_float(((unsigned int)h) << 16);
}

// ---------------- k0a: T = w3@w2 [64][256] per graph, b_eff = w3@(w2@b1+b2)+b3 ----------------
__global__ void k0a(const float* __restrict__ w2a, const float* __restrict__ w3a,
                    const float* __restrict__ b1a, const float* __restrict__ b2a, const float* __restrict__ b3a,
                    const float* __restrict__ w2b, const float* __restrict__ w3b,
                    const float* __restrict__ b1b, const float* __restrict__ b2b, const float* __restrict__ b3b,
                    float* __restrict__ T, float* __restrict__ beff) {
    const int g  = blockIdx.x >> 5;
    const int nb = blockIdx.x & 31;
    const float* w2 = g ? w2b : w2a;   // [128][256]
    const float* w3 = g ? w3b : w3a;   // [64][128]
    const int c  = threadIdx.x;
    const int n0 = nb * 2;
    float a0 = 0.f, a1 = 0.f;
#pragma unroll 8
    for (int r = 0; r < 128; ++r) {
        float w = w2[r * 256 + c];
        a0 += w3[n0 * 128 + r] * w;            // block-uniform -> s_load
        a1 += w3[n0 * 128 + 128 + r] * w;
    }
    float* Tg = T + g * 64 * 256;
    Tg[n0 * 256 + c]       = a0;
    Tg[(n0 + 1) * 256 + c] = a1;

    if (nb == 0) {                              // bias path (biases zero in setup; compute anyway)
        __shared__ float u[128];
        const float* b1 = g ? b1b : b1a;
        const float* b2 = g ? b2b : b2a;
        const float* b3 = g ? b3b : b3a;
        if (threadIdx.x < 128) {
            int r = threadIdx.x;
            float s = 0.f;
            for (int cc = 0; cc < 256; ++cc) s += w2[r * 256 + cc] * b1[cc];
            u[r] = s + b2[r];
        }
        __syncthreads();
        if (threadIdx.x < 64) {
            int n = threadIdx.x;
            float s = 0.f;
            for (int r = 0; r < 128; ++r) s += w3[n * 128 + r] * u[r];
            beff[g * 64 + n] = s + b3[n];
        }
    }
}

// ---------------- k0b: Weff = T@w1 -> split bf16 (hi + lo planes), n-major ----------------
__global__ void k0b(const float* __restrict__ w1a, const float* __restrict__ w1b,
                    const float* __restrict__ T,
                    unsigned short* __restrict__ Whi, unsigned short* __restrict__ Wlo) {
    const int b  = blockIdx.x;
    const int g  = b >> 7, n8 = (b >> 4) & 7, kc = b & 15;
    const float* w1 = g ? w1b : w1a;                  // [256][4096]
    const float* Tg = T + (g * 64 + n8 * 8) * 256;    // block-uniform rows -> s_load
    const int kx = kc * 256 + threadIdx.x;
    float acc[8] = {0, 0, 0, 0, 0, 0, 0, 0};
#pragma unroll 8
    for (int r = 0; r < 256; ++r) {
        float w = w1[r * N + kx];
#pragma unroll
        for (int j = 0; j < 8; ++j) acc[j] += Tg[j * 256 + r] * w;
    }
#pragma unroll
    for (int j = 0; j < 8; ++j) {
        size_t idx = (size_t)(g * 64 + n8 * 8 + j) * N + kx;
        unsigned short hi = f2bf(acc[j]);
        Whi[idx] = hi;
        Wlo[idx] = f2bf(acc[j] - bf2f(hi));
    }
}

// ---------------- k1: h = relu(x @ Weff.T + beff), split-bf16, barrier-free K-loop ----------------
// 4 waves = 4 K-groups (1024 each); each wave computes all 4 n-groups; direct fragment loads.
__global__ __launch_bounds__(256) void k1(const float* __restrict__ x1, const float* __restrict__ x2,
                                          const unsigned short* __restrict__ Whi,
                                          const unsigned short* __restrict__ Wlo,
                                          const float* __restrict__ beff,
                                          float* __restrict__ hf, unsigned short* __restrict__ hT) {
    const int b  = blockIdx.x;
    const int g  = b & 1;
    const int i0 = (b >> 1) * 16;
    const float* x = g ? x2 : x1;
    const size_t goff = (size_t)g * 64 * N;

    const int t = threadIdx.x;
    const int lane = t & 63, kg = t >> 6;           // wave = K-group
    const int q = lane >> 4, l15 = lane & 15;

    __shared__ float accs[4][4][64][4];             // [kg][ng][lane][r] = 16 KB

    f32x4 acc[4];
#pragma unroll
    for (int ng = 0; ng < 4; ++ng) acc[ng] = (f32x4){0.f, 0.f, 0.f, 0.f};

    const float* xrow = x + (size_t)(i0 + l15) * N;
    for (int kk = 0; kk < 16; ++kk) {
#pragma unroll
        for (int c = 0; c < 2; ++c) {
            const int ka = kg * 1024 + kk * 64 + c * 32 + q * 8;
            float4 a0 = *(const float4*)&xrow[ka];
            float4 a1 = *(const float4*)&xrow[ka + 4];
            s16x8 bh[4], bl[4];
#pragma unroll
            for (int ng = 0; ng < 4; ++ng) {
                const size_t bo = goff + (size_t)(ng * 16 + l15) * N + ka;
                bh[ng] = *(const s16x8*)&Whi[bo];
                bl[ng] = *(const s16x8*)&Wlo[bo];
            }
            float xv[8] = {a0.x, a0.y, a0.z, a0.w, a1.x, a1.y, a1.z, a1.w};
            s16x8 ah, al;
#pragma unroll
            for (int j = 0; j < 8; ++j) {
                unsigned short h = f2bf(xv[j]);
                ah[j] = (short)h;
                al[j] = (short)f2bf(xv[j] - bf2f(h));
            }
#pragma unroll
            for (int ng = 0; ng < 4; ++ng) {
                acc[ng] = __builtin_amdgcn_mfma_f32_16x16x32_bf16(al, bh[ng], acc[ng], 0, 0, 0);
                acc[ng] = __builtin_amdgcn_mfma_f32_16x16x32_bf16(ah, bl[ng], acc[ng], 0, 0, 0);
                acc[ng] = __builtin_amdgcn_mfma_f32_16x16x32_bf16(ah, bh[ng], acc[ng], 0, 0, 0);
            }
        }
    }
#pragma unroll
    for (int ng = 0; ng < 4; ++ng)
#pragma unroll
        for (int r = 0; r < 4; ++r) accs[kg][ng][lane][r] = acc[ng][r];
    __syncthreads();

    const int n = kg * 16 + l15;                    // wave kg takes over n-group kg
    const float be = beff[g * 64 + n];
    unsigned short pk[4];
#pragma unroll
    for (int r = 0; r < 4; ++r) {
        float v = accs[0][kg][lane][r] + accs[1][kg][lane][r]
                + accs[2][kg][lane][r] + accs[3][kg][lane][r] + be;
        v = fmaxf(v, 0.f);
        hf[(size_t)(g * N + i0 + q * 4 + r) * 64 + n] = v;
        pk[r] = f2bf(v);
    }
    *(ushort4*)&hT[(size_t)(g * 64 + n) * N + i0 + q * 4] = make_ushort4(pk[0], pk[1], pk[2], pk[3]);
}

// ---------------- k2: agg = (adj==1)*alpha @ h, both graphs, barrier-free K-loop ----------------
__global__ __launch_bounds__(256) void k2(const int* __restrict__ adj1, const int* __restrict__ adj2,
                                          const float* __restrict__ alpha, const float* __restrict__ Wp,
                                          const unsigned short* __restrict__ hT, const float* __restrict__ hf,
                                          float* __restrict__ outv) {
    const int i0 = blockIdx.x * 16;
    const int t = threadIdx.x;
    const int lane = t & 63, kg = t >> 6;           // wave = K-group
    const int q = lane >> 4, l15 = lane & 15;

    __shared__ float accs[4][4][64][8];             // [kg][ng][lane][g*4+r] = 32 KB
    __shared__ float degp[4][64][2];                // per-wave per-lane partial deg
    __shared__ float degf[2][16];

    f32x4 acc[4][2];
#pragma unroll
    for (int ng = 0; ng < 4; ++ng) {
        acc[ng][0] = (f32x4){0.f, 0.f, 0.f, 0.f};
        acc[ng][1] = (f32x4){0.f, 0.f, 0.f, 0.f};
    }
    int deg1 = 0, deg2 = 0;

    const size_t rowoff = (size_t)(i0 + l15) * N;
    for (int kk = 0; kk < 16; ++kk) {
#pragma unroll
        for (int c = 0; c < 2; ++c) {
            const int ka = kg * 1024 + kk * 64 + c * 32 + q * 8;
            const size_t ao = rowoff + ka;
            float4 a0 = *(const float4*)&alpha[ao];
            float4 a1 = *(const float4*)&alpha[ao + 4];
            int4 j10 = *(const int4*)&adj1[ao];
            int4 j11 = *(const int4*)&adj1[ao + 4];
            int4 j20 = *(const int4*)&adj2[ao];
            int4 j21 = *(const int4*)&adj2[ao + 4];
            s16x8 b1[4], b2[4];
#pragma unroll
            for (int ng = 0; ng < 4; ++ng) {
                const size_t bo = (size_t)(ng * 16 + l15) * N + ka;
                b1[ng] = *(const s16x8*)&hT[bo];
                b2[ng] = *(const s16x8*)&hT[(size_t)64 * N + bo];
            }
            float av[8] = {a0.x, a0.y, a0.z, a0.w, a1.x, a1.y, a1.z, a1.w};
            int m1[8] = {j10.x == 1, j10.y == 1, j10.z == 1, j10.w == 1,
                         j11.x == 1, j11.y == 1, j11.z == 1, j11.w == 1};
            int m2[8] = {j20.x == 1, j20.y == 1, j20.z == 1, j20.w == 1,
                         j21.x == 1, j21.y == 1, j21.z == 1, j21.w == 1};
            s16x8 af1, af2;
#pragma unroll
            for (int j = 0; j < 8; ++j) {
                short bv = (short)f2bf(av[j]);
                af1[j] = m1[j] ? bv : (short)0;
                af2[j] = m2[j] ? bv : (short)0;
                deg1 += m1[j];
                deg2 += m2[j];
            }
#pragma unroll
            for (int ng = 0; ng < 4; ++ng) {
                acc[ng][0] = __builtin_amdgcn_mfma_f32_16x16x32_bf16(af1, b1[ng], acc[ng][0], 0, 0, 0);
                acc[ng][1] = __builtin_amdgcn_mfma_f32_16x16x32_bf16(af2, b2[ng], acc[ng][1], 0, 0, 0);
            }
        }
    }
#pragma unroll
    for (int ng = 0; ng < 4; ++ng)
#pragma unroll
        for (int gg = 0; gg < 2; ++gg)
#pragma unroll
            for (int r = 0; r < 4; ++r) accs[kg][ng][lane][gg * 4 + r] = acc[ng][gg][r];
    degp[kg][lane][0] = (float)deg1;
    degp[kg][lane][1] = (float)deg2;
    __syncthreads();
    if (t < 32) {                                   // deg over (4 waves x 4 q-slices)
        int gg = t >> 4, row = t & 15;
        float s = 0.f;
#pragma unroll
        for (int w = 0; w < 4; ++w)
#pragma unroll
            for (int qq = 0; qq < 4; ++qq) s += degp[w][qq * 16 + row][gg];
        degf[gg][row] = s;
    }
    __syncthreads();

    const float W00 = Wp[0];
    const int n = kg * 16 + l15;                    // wave kg takes over n-group kg
#pragma unroll
    for (int r = 0; r < 4; ++r) {
        int iloc = q * 4 + r;
        int i = i0 + iloc;
        float s1 = accs[0][kg][lane][r] + accs[1][kg][lane][r]
                 + accs[2][kg][lane][r] + accs[3][kg][lane][r];
        float s2 = accs[0][kg][lane][4 + r] + accs[1][kg][lane][4 + r]
                 + accs[2][kg][lane][4 + r] + accs[3][kg][lane][4 + r];
        float dg1 = degf[0][iloc], dg2 = degf[1][iloc];
        float hv1 = hf[(size_t)i * 64 + n];
        outv[(size_t)i * 64 + n] = (dg1 != 0.f) ? (s1 * W00 / fmaxf(dg1, 1.f) + hv1) : 0.f;
        float hv2 = hf[(size_t)(N + i) * 64 + n];
        outv[(size_t)(N + i) * 64 + n] = (dg2 != 0.f) ? (s2 * W00 / fmaxf(dg2, 1.f) + hv2) : 0.f;
    }
}

// ---------------- k3a/k3b: out = feat @ clf_w.T + clf_b (two-stage deterministic reduction) ----------------
__global__ __launch_bounds__(256) void k3a(const float* __restrict__ feat, const float* __restrict__ clfw,
                                           float* __restrict__ part) {
    const int t = threadIdx.x;
    const size_t idx = (size_t)blockIdx.x * 2048 + (size_t)t * 8;
    float4 a0 = *(const float4*)&feat[idx];
    float4 a1 = *(const float4*)&feat[idx + 4];
    float4 c0 = *(const float4*)&clfw[idx];
    float4 c1 = *(const float4*)&clfw[idx + 4];
    float4 d0 = *(const float4*)&clfw[524288 + idx];
    float4 d1 = *(const float4*)&clfw[524288 + idx + 4];
    float s0 = a0.x * c0.x + a0.y * c0.y + a0.z * c0.z + a0.w * c0.w
             + a1.x * c1.x + a1.y * c1.y + a1.z * c1.z + a1.w * c1.w;
    float s1 = a0.x * d0.x + a0.y * d0.y + a0.z * d0.z + a0.w * d0.w
             + a1.x * d1.x + a1.y * d1.y + a1.z * d1.z + a1.w * d1.w;
    __shared__ float r0[256], r1[256];
    r0[t] = s0; r1[t] = s1;
    __syncthreads();
    for (int s = 128; s > 0; s >>= 1) {
        if (t < s) { r0[t] += r0[t + s]; r1[t] += r1[t + s]; }
        __syncthreads();
    }
    if (t == 0) { part[blockIdx.x * 2] = r0[0]; part[blockIdx.x * 2 + 1] = r1[0]; }
}

__global__ void k3b(const float* __restrict__ part, const float* __restrict__ clfb,
                    float* __restrict__ outp) {
    const int t = threadIdx.x;
    __shared__ float r0[256], r1[256];
    r0[t] = part[t * 2]; r1[t] = part[t * 2 + 1];
    __syncthreads();
    for (int s = 128; s > 0; s >>= 1) {
        if (t < s) { r0[t] += r0[t + s]; r1[t] += r1[t + s]; }
        __syncthreads();
    }
    if (t == 0) { outp[0] = r0[0] + clfb[0]; outp[1] = r1[0] + clfb[1]; }
}

extern "C" void kernel_launch(void* const* d_in, const int* in_sizes, int n_in,
                              void* d_out, int out_size, void* d_ws, size_t ws_size,
                              hipStream_t stream) {
    const float* x1   = (const float*)d_in[0];
    const float* x2   = (const float*)d_in[1];
    const int*   adj1 = (const int*)d_in[2];
    const int*   adj2 = (const int*)d_in[3];
    const float* e1w1 = (const float*)d_in[4];
    const float* e1b1 = (const float*)d_in[5];
    const float* e1w2 = (const float*)d_in[6];
    const float* e1b2 = (const float*)d_in[7];
    const float* e1w3 = (const float*)d_in[8];
    const float* e1b3 = (const float*)d_in[9];
    const float* e2w1 = (const float*)d_in[10];
    const float* e2b1 = (const float*)d_in[11];
    const float* e2w2 = (const float*)d_in[12];
    const float* e2b2 = (const float*)d_in[13];
    const float* e2w3 = (const float*)d_in[14];
    const float* e2b3 = (const float*)d_in[15];
    const float* Wp   = (const float*)d_in[16];
    const float* alph = (const float*)d_in[17];
    const float* clfw = (const float*)d_in[18];
    const float* clfb = (const float*)d_in[19];

    char* wsb = (char*)d_ws;
    // Weff hi/lo (2 MB) live through k1; newv (2 MB) aliases them from k2 on.
    unsigned short* Whi = (unsigned short*)(wsb);                        // 1 MB
    unsigned short* Wlo = (unsigned short*)(wsb + (1u << 20));           // 1 MB
    float* newv = (float*)(wsb);                                         // 2 MB (aliases Whi/Wlo)
    unsigned short* hT  = (unsigned short*)(wsb + (2u << 20));           // 1 MB
    float* hf   = (float*)(wsb + (3u << 20));                            // 2 MB
    float* T    = (float*)(wsb + (5u << 20));                            // 128 KB
    float* beff = (float*)(wsb + (5u << 20) + (1u << 17));               // 512 B
    float* part = (float*)(wsb + (5u << 20) + (1u << 17) + 4096);        // 2 KB

    hipLaunchKernelGGL(k0a, dim3(64), dim3(256), 0, stream,
                       e1w2, e1w3, e1b1, e1b2, e1b3, e2w2, e2w3, e2b1, e2b2, e2b3, T, beff);
    hipLaunchKernelGGL(k0b, dim3(256), dim3(256), 0, stream, e1w1, e2w1, T, Whi, Wlo);
    hipLaunchKernelGGL(k1, dim3(512), dim3(256), 0, stream, x1, x2, Whi, Wlo, beff, hf, hT);
    hipLaunchKernelGGL(k2, dim3(256), dim3(256), 0, stream, adj1, adj2, alph, Wp, hT, hf, newv);
    hipLaunchKernelGGL(k3a, dim3(256), dim3(256), 0, stream, newv, clfw, part);
    hipLaunchKernelGGL(k3b, dim3(1), dim3(256), 0, stream, part, clfb, (float*)d_out);
}